// Round 2
// baseline (877.247 us; speedup 1.0000x reference)
//
#include <hip/hip_runtime.h>
#include <math.h>

#define Bn 16
#define Ln 2500
#define En 100
#define FM 50
#define Yn 8921
#define KS 10
#define LP 2501
#define NT 40              // 40 tiles of 64 l (2560 >= 2501)
#define TILE_BYTES 19456   // hA 10240 + hT 9216
#define TILE_SHORTS 9728
#define HT_OFF 5120        // shorts
#define CH_FULL 19         // 1KB chunks per full tile
#define CH_A 10            // chunks covering hA only

typedef __attribute__((ext_vector_type(8))) short short8;
typedef __attribute__((ext_vector_type(4))) float f32x4;

union S8 { short8 v; long l2[2]; short s[8]; };

__device__ __forceinline__ short f2bf(float f){
  unsigned u = __float_as_uint(f);
  unsigned r = (u + 0x7fffu + ((u >> 16) & 1u)) >> 16;
  return (short)r;
}

// async 16B/lane global->LDS
__device__ __forceinline__ void g2l16(const void* g, void* l){
  __builtin_amdgcn_global_load_lds(
      (const __attribute__((address_space(1))) unsigned int*)g,
      (__attribute__((address_space(3))) unsigned int*)l, 16, 0, 0);
}

__device__ __forceinline__ void stage_chunks(const char* __restrict__ gbase,
                                             char* lbase, int wave, int lane, int nch){
  for (int chunk = wave; chunk < nch; chunk += 4)
    g2l16(gbase + chunk * 1024 + lane * 16, lbase + chunk * 1024 + lane * 16);
}

// ---------------- K0: transpose conv_w (Fm,E,K) -> WT[e*10+k][f(64 pad0)] --------------
__global__ void k0_wt(const float* __restrict__ cw, float* __restrict__ WT){
  int i = blockIdx.x * 256 + threadIdx.x;
  if (i < 64000){
    int f = i & 63, ek = i >> 6;
    WT[i] = (f < FM) ? cw[f * 1000 + ek] : 0.f;
  }
}

// ---------------- K1: conv+bias+tanh -> per-tile blob [hA pad | hT pad] bf16 -----------
__global__ __launch_bounds__(256) void k1_conv(
    const float* __restrict__ x, const float* __restrict__ WT,
    const float* __restrict__ conv_b, short* __restrict__ Hp)
{
  int t = blockIdx.x, b = blockIdx.y, tid = threadIdx.x;
  __shared__ float x_s[100 * 76];       // [e][row(73) pad 76]
  __shared__ short h_t[64 * 69];        // [l][f pad 69]

  int r0 = 64 * t - 5;
  for (int d = tid; d < 7300; d += 256){
    int row = d / 100, e = d - row * 100;
    int gr = r0 + row;
    float v = (gr >= 0 && gr < Ln) ? x[((size_t)b * Ln + gr) * 100 + e] : 0.f;
    x_s[e * 76 + row] = v;
  }
  __syncthreads();

  int f = tid & 63, lsub = tid >> 6;
  float acc[16];
#pragma unroll
  for (int j = 0; j < 16; j++) acc[j] = 0.f;

  for (int e = 0; e < 100; e++){
    float xv[25];
    const float* xr = x_s + e * 76 + lsub * 16;
#pragma unroll
    for (int i = 0; i < 6; i++){
      f32x4 q = *(const f32x4*)(xr + 4 * i);
      xv[4*i+0] = q[0]; xv[4*i+1] = q[1]; xv[4*i+2] = q[2]; xv[4*i+3] = q[3];
    }
    xv[24] = xr[24];
#pragma unroll
    for (int k = 0; k < KS; k++){
      float wv = WT[(e * 10 + k) * 64 + f];
#pragma unroll
      for (int j = 0; j < 16; j++) acc[j] += wv * xv[j + k];
    }
  }

  float bias = (f < FM) ? conv_b[f] : 0.f;
  size_t tbS = (size_t)(b * NT + t) * TILE_SHORTS;
#pragma unroll
  for (int j = 0; j < 16; j++){
    int l = lsub * 16 + j;
    int lgl = 64 * t + l;
    float hv = (lgl < LP && f < FM) ? tanhf(acc[j] + bias) : 0.f;
    short hb = f2bf(hv);
    // hA image: [fgrp(4)][l(64)][20]  (cols 16..19 are unread holes)
    Hp[tbS + (size_t)(f >> 4) * 1280 + (size_t)l * 20 + (f & 15)] = hb;
    h_t[l * 69 + f] = hb;
  }
  __syncthreads();
  int lane = tid & 63, wave = tid >> 6;
#pragma unroll
  for (int i = 0; i < 16; i++){
    int fo = wave + 4 * i;
    // hT image: [f(64)][72]  (cols 64..71 unread holes)
    Hp[tbS + HT_OFF + (size_t)fo * 72 + lane] = h_t[lane * 69 + fo];
  }
}

// ---------------- K2 fragment compute ----------------
__device__ __forceinline__ void scores_tile(const short* __restrict__ h_s,
                                            const S8 bu[2], int c, int g, f32x4 d[4])
{
#pragma unroll
  for (int ms = 0; ms < 4; ms++){
    f32x4 acc = {0.f, 0.f, 0.f, 0.f};
#pragma unroll
    for (int kf = 0; kf < 2; kf++){
      const short* pa = h_s + (2 * kf) * 1280 + (c + 16 * ms) * 20 + 4 * g;
      S8 a;
      a.l2[0] = *(const long*)pa;
      a.l2[1] = *(const long*)(pa + 1280);
      acc = __builtin_amdgcn_mfma_f32_16x16x32_bf16(a.v, bu[kf].v, acc, 0, 0, 0);
    }
    d[ms] = acc;
  }
}

// ---------------- K2: fused scores -> softmax -> alpha write -> m -> logits ------------
__global__ __launch_bounds__(256) void k2_attn(
    const short* __restrict__ Hp,
    const float* __restrict__ U_w, const float* __restrict__ final_w,
    const float* __restrict__ final_b,
    float* __restrict__ logits, float* __restrict__ alpha_out)
{
  int b = blockIdx.y;
  int y0 = blockIdx.x * 64;
  int tid = threadIdx.x;
  int lane = tid & 63, wave = tid >> 6;
  int c = lane & 15, g = lane >> 4;
  int ywave = y0 + wave * 16;

  __shared__ __align__(16) short buf[2][TILE_SHORTS];
  __shared__ float aw_s[4][16 * 37];

  // B1 fragments from U_w (k-slot convention matches A fragments)
  S8 bu[2];
  {
    int yv = ywave + c;
#pragma unroll
    for (int kf = 0; kf < 2; kf++)
#pragma unroll
      for (int i = 0; i < 8; i++){
        int fidx = 4 * g + (i & 3) + 16 * (i >> 2) + 32 * kf;
        float v = (yv < Yn && fidx < FM) ? U_w[yv * FM + fidx] : 0.f;
        bu[kf].s[i] = f2bf(v);
      }
  }

  const char* blob = (const char*)Hp + (size_t)b * NT * TILE_BYTES;

  // ---- pass 1: S = sum_l exp(score)  (no max subtraction: |score| < ~3) ----
  float S = 0.f;
  int cur = 0;
  stage_chunks(blob, (char*)buf[0], wave, lane, CH_A);
  for (int t = 0; t < NT; t++){
    __syncthreads();                       // drains vmcnt -> buf[cur] ready
    if (t + 1 < NT)
      stage_chunks(blob + (size_t)(t + 1) * TILE_BYTES, (char*)buf[cur ^ 1], wave, lane, CH_A);
    f32x4 d[4];
    scores_tile(buf[cur], bu, c, g, d);
    if (t < NT - 1){
#pragma unroll
      for (int ms = 0; ms < 4; ms++)
#pragma unroll
        for (int r = 0; r < 4; r++) S += __expf(d[ms][r]);
    } else {
#pragma unroll
      for (int ms = 0; ms < 4; ms++)
#pragma unroll
        for (int r = 0; r < 4; r++){
          int l = 64 * t + 16 * ms + 4 * g + r;
          if (l < LP) S += __expf(d[ms][r]);
        }
    }
    cur ^= 1;
  }
  S += __shfl_xor(S, 16);
  S += __shfl_xor(S, 32);
  float invS = 1.f / S;

  // ---- pass 2: alpha (write) + m accumulate ----
  f32x4 m2[4];
#pragma unroll
  for (int fs = 0; fs < 4; fs++) m2[fs] = (f32x4){0.f, 0.f, 0.f, 0.f};

  __syncthreads();                          // pass1 compute fully done before restage
  stage_chunks(blob, (char*)buf[cur], wave, lane, CH_FULL);
  for (int t = 0; t < NT; t++){
    __syncthreads();
    if (t + 1 < NT)
      stage_chunks(blob + (size_t)(t + 1) * TILE_BYTES, (char*)buf[cur ^ 1], wave, lane, CH_FULL);
    const short* h_s  = buf[cur];
    const short* ht_s = buf[cur] + HT_OFF;
    f32x4 d[4];
    scores_tile(h_s, bu, c, g, d);
    float a[16];
    if (t < NT - 1){
#pragma unroll
      for (int ms = 0; ms < 4; ms++)
#pragma unroll
        for (int r = 0; r < 4; r++) a[ms * 4 + r] = __expf(d[ms][r]) * invS;
    } else {
#pragma unroll
      for (int ms = 0; ms < 4; ms++)
#pragma unroll
        for (int r = 0; r < 4; r++){
          int l = 64 * t + 16 * ms + 4 * g + r;
          a[ms * 4 + r] = (l < LP) ? __expf(d[ms][r]) * invS : 0.f;
        }
    }

    // GEMM2: m += alpha * h   (A2 repacked in-lane from scores^T fragments)
#pragma unroll
    for (int kl = 0; kl < 2; kl++){
      S8 a2;
#pragma unroll
      for (int i = 0; i < 8; i++)
        a2.s[i] = f2bf(a[(2 * kl + (i >> 2)) * 4 + (i & 3)]);
#pragma unroll
      for (int fs = 0; fs < 4; fs++){
        const short* pb = ht_s + (16 * fs + c) * 72 + 4 * g + 32 * kl;
        S8 b2;
        b2.l2[0] = *(const long*)pb;
        b2.l2[1] = *(const long*)(pb + 16);
        m2[fs] = __builtin_amdgcn_mfma_f32_16x16x32_bf16(a2.v, b2.v, m2[fs], 0, 0, 0);
      }
    }

    // alpha -> per-wave LDS transpose (2 rounds of 32 l), coalesced 128B-row stores
    float* aw = aw_s[wave];
#pragma unroll
    for (int ms2 = 0; ms2 < 2; ms2++){
#pragma unroll
      for (int mh = 0; mh < 2; mh++)
#pragma unroll
        for (int r = 0; r < 4; r++)
          aw[c * 37 + 16 * mh + 4 * g + r] = a[(2 * ms2 + mh) * 4 + r];
      // wave-internal: compiler inserts lgkmcnt waits, no barrier needed
      int col = lane & 31;
      int jhi = lane >> 5;
#pragma unroll
      for (int j0 = 0; j0 < 16; j0 += 2){
        int j = j0 + jhi;
        int yj = ywave + j;
        int lg = 64 * t + 32 * ms2 + col;
        if (yj < Yn && lg < LP)
          alpha_out[((size_t)b * Yn + yj) * LP + lg] = aw[j * 37 + col];
      }
    }
    cur ^= 1;
  }

  // ---- epilogue: logits ----
  float part[4];
#pragma unroll
  for (int r = 0; r < 4; r++){
    int yy = ywave + 4 * g + r;
    float p = 0.f;
    if (yy < Yn){
#pragma unroll
      for (int fs = 0; fs < 4; fs++){
        int fcol = fs * 16 + c;
        if (fcol < FM) p += m2[fs][r] * final_w[yy * FM + fcol];
      }
    }
#pragma unroll
    for (int off = 1; off <= 8; off <<= 1) p += __shfl_xor(p, off);
    part[r] = p;
  }
  if (c == 0){
#pragma unroll
    for (int r = 0; r < 4; r++){
      int yy = ywave + 4 * g + r;
      if (yy < Yn) logits[(size_t)b * Yn + yy] = part[r] + final_b[yy];
    }
  }
}

// ---------------- K3: log_softmax over Y + BCE loss partials ----------------
__global__ __launch_bounds__(256) void k3_lsm(
    const float* __restrict__ logits, const float* __restrict__ target,
    float* __restrict__ proba, float* __restrict__ lossp)
{
  int b = blockIdx.x, tid = threadIdx.x;
  int lane = tid & 63, wave = tid >> 6;
  __shared__ float red[4];
  const float* lg = logits + (size_t)b * Yn;
  const float* tg = target + (size_t)b * Yn;

  float m = -INFINITY;
  for (int y = tid; y < Yn; y += 256) m = fmaxf(m, lg[y]);
#pragma unroll
  for (int off = 1; off <= 32; off <<= 1) m = fmaxf(m, __shfl_xor(m, off));
  if (lane == 0) red[wave] = m;
  __syncthreads();
  m = fmaxf(fmaxf(red[0], red[1]), fmaxf(red[2], red[3]));
  __syncthreads();

  float s = 0.f;
  for (int y = tid; y < Yn; y += 256) s += __expf(lg[y] - m);
#pragma unroll
  for (int off = 1; off <= 32; off <<= 1) s += __shfl_xor(s, off);
  if (lane == 0) red[wave] = s;
  __syncthreads();
  s = red[0] + red[1] + red[2] + red[3];
  __syncthreads();
  float lse = m + logf(s);

  float ls = 0.f;
  for (int y = tid; y < Yn; y += 256){
    float xx = lg[y];
    proba[(size_t)b * Yn + y] = xx - lse;
    ls += fmaxf(xx, 0.f) - xx * tg[y] + log1pf(__expf(-fabsf(xx)));
  }
#pragma unroll
  for (int off = 1; off <= 32; off <<= 1) ls += __shfl_xor(ls, off);
  if (lane == 0) red[wave] = ls;
  __syncthreads();
  if (tid == 0) lossp[b] = red[0] + red[1] + red[2] + red[3];
}

__global__ void k4_loss(const float* __restrict__ lossp, float* __restrict__ out){
  if (threadIdx.x == 0){
    float s = 0.f;
    for (int i = 0; i < Bn; i++) s += lossp[i];
    out[142736] = s / 142736.f;
  }
}

// ---------------- launch ----------------
extern "C" void kernel_launch(void* const* d_in, const int* in_sizes, int n_in,
                              void* d_out, int out_size, void* d_ws, size_t ws_size,
                              hipStream_t stream)
{
  const float* x       = (const float*)d_in[0];
  const float* target  = (const float*)d_in[1];
  const float* conv_w  = (const float*)d_in[2];
  const float* conv_b  = (const float*)d_in[3];
  const float* U_w     = (const float*)d_in[4];
  const float* final_w = (const float*)d_in[5];
  const float* final_b = (const float*)d_in[6];
  float* out = (float*)d_out;

  char* ws = (char*)d_ws;
  short* Hp     = (short*)(ws);                 // 16*40*19456 = 12,451,840 B
  float* WT     = (float*)(ws + 12451840);      //   256,000 B
  float* logits = (float*)(ws + 12707840);      //   570,944 B
  float* lossp  = (float*)(ws + 13278784);      //        64 B

  float* proba     = out;              // B*Y
  float* alpha_out = out + 142737;     // after proba + loss

  k0_wt<<<dim3(250), dim3(256), 0, stream>>>(conv_w, WT);
  k1_conv<<<dim3(NT, Bn), dim3(256), 0, stream>>>(x, WT, conv_b, Hp);
  k2_attn<<<dim3(140, Bn), dim3(256), 0, stream>>>(Hp, U_w, final_w, final_b,
                                                   logits, alpha_out);
  k3_lsm<<<dim3(Bn), dim3(256), 0, stream>>>(logits, target, proba, lossp);
  k4_loss<<<dim3(1), dim3(64), 0, stream>>>(lossp, out);
}